// Round 14
// baseline (179.409 us; speedup 1.0000x reference)
//
#include <hip/hip_runtime.h>
#include <hip/hip_bf16.h>

constexpr int LAYERS = 24;
constexpr int DIM    = 2048;
constexpr int NBLK   = 8;
constexpr float EPSV = 1e-6f;
constexpr int TPB    = 512;
constexpr int EPT    = 4;            // one float4 slice per thread
constexpr int NSLOT  = 147;          // total block-wide reduced scalars
constexpr int RSTR   = NSLOT + 2;    // odd stride

typedef float vf4 __attribute__((ext_vector_type(4)));

// Reduced-value layout (slot indices):
//   slot 0: ssq(emb)
//   layer l (1..23), m=l/3, i=l%3, off=OFF_TAB[l]:
//     off+0        : dot(emb, qw_l)
//     off+1+s      : dot(S_s, qw_l)          s = 0..m-1
//     i>0:  off+m+1: dot(part_l, qw_l),  off+m+2: ssq(part_l)
//     i==0: off+m+1: ssq(S_{m-1})
// Batches: A=layers 1..7 slots [0,27), B=8..15 [27,76), C=16..23 [76,147)
__device__ constexpr int OFF_TAB[24] =
    {0,1,4,7,10,14,18,22,27,32,37,43,49,55,62,69,76,84,92,100,109,118,127,137};

__device__ __forceinline__ unsigned pk2(float a, float b) {
    __hip_bfloat162 h2(__float2bfloat16(a), __float2bfloat16(b));
    union { __hip_bfloat162 h; unsigned u; } c; c.h = h2; return c.u;
}
__device__ __forceinline__ float upk(unsigned p, int hi) {
    union { unsigned u; float f; } c;
    c.u = hi ? (p & 0xffff0000u) : (p << 16);
    return c.f;
}

// DPP tree ops over each 16-lane group (pure VALU, no DS pipe).
template<int CTRL>
__device__ __forceinline__ float dpp_nbor(float x) {
    int y = __builtin_amdgcn_update_dpp(0, __float_as_int(x), CTRL, 0xF, 0xF, true);
    return __int_as_float(y);
}
__device__ __forceinline__ float grp16_sum(float x) {
    x += dpp_nbor<0xB1>(x);     // quad_perm[1,0,3,2]
    x += dpp_nbor<0x4E>(x);     // quad_perm[2,3,0,1]
    x += dpp_nbor<0x141>(x);    // row_half_mirror
    x += dpp_nbor<0x140>(x);    // row_mirror
    return x;
}
__device__ __forceinline__ float grp16_max(float x) {
    x = fmaxf(x, dpp_nbor<0xB1>(x));
    x = fmaxf(x, dpp_nbor<0x4E>(x));
    x = fmaxf(x, dpp_nbor<0x141>(x));
    x = fmaxf(x, dpp_nbor<0x140>(x));
    return x;
}

__global__ void __launch_bounds__(TPB, 4)   // cap 128 unified regs; demand ~100
block_attn_res_kernel(const float* __restrict__ lo,   // (L, B*T, D)
                      const float* __restrict__ emb,  // (B*T, D)
                      const float* __restrict__ qry,  // (L, D)
                      const float* __restrict__ wgt,  // (D)
                      float* __restrict__ out,        // (L, B*T, D)
                      int bt_total)
{
    const int bt   = blockIdx.x;
    const int tid  = threadIdx.x;
    const int lane = tid & 63;
    const int wid  = tid >> 6;
    const int grp  = (wid << 2) | (lane >> 4);   // 16-lane group id, 0..31
    const int c0   = tid * 4;                    // thread owns d-indices [4t,4t+4)

    __shared__ float red[32][RSTR];        // group partials (written once per slot)
    __shared__ float ab[LAYERS][12];       // normalized alphas per layer

    const float invD = 1.f / (float)DIM;
    const size_t lstride = (size_t)bt_total * DIM;
    const float* lop = lo + (size_t)bt * DIM + c0;

    // 16-lane DPP tree sum; group leader writes LDS
    auto wred = [&](float x, int slot) {
        x = grp16_sum(x);
        if ((lane & 15) == 0) red[grp][slot] = x;
    };

    // weight slice (folded into q row per layer)
    float wv[EPT];
    {
        vf4 w0 = *reinterpret_cast<const vf4*>(wgt + c0);
        wv[0]=w0.x; wv[1]=w0.y; wv[2]=w0.z; wv[3]=w0.w;
    }

    // ---- embedding slice
    float e[EPT];
    {
        vf4 v0 = __builtin_nontemporal_load(
            reinterpret_cast<const vf4*>(emb + (size_t)bt * DIM + c0));
        e[0]=v0.x; e[1]=v0.y; e[2]=v0.z; e[3]=v0.w;
    }

    unsigned pp[16][EPT/2];       // part snapshots at the 16 i>0 layers, bf16x2
    unsigned Spk[NBLK-1][EPT/2];  // finished block sums S_0..S_6, bf16x2
    float part[EPT];              // running within-block partial (f32)

    // output emission for one layer (l compile-time under unroll)
    auto emit = [&](int l) {
        const int m = l / 3;
        const int i = l - 3 * m;
        float h[EPT];
        {
            const float a0 = ab[l][0];
            #pragma unroll
            for (int j = 0; j < EPT; ++j) h[j] = a0 * e[j];
        }
        #pragma unroll
        for (int s = 0; s < NBLK - 1; ++s) {
            if (s < m) {
                const float a = ab[l][1 + s];
                h[0] += a * upk(Spk[s][0],0);
                h[1] += a * upk(Spk[s][0],1);
                h[2] += a * upk(Spk[s][1],0);
                h[3] += a * upk(Spk[s][1],1);
            }
        }
        if (i > 0) {
            const float a = ab[l][1 + m];
            const int si = 2 * m + (i - 1);
            h[0] += a * upk(pp[si][0],0);
            h[1] += a * upk(pp[si][0],1);
            h[2] += a * upk(pp[si][1],0);
            h[3] += a * upk(pp[si][1],1);
        }
        vf4 w0; w0.x=h[0]; w0.y=h[1]; w0.z=h[2]; w0.w=h[3];
        *reinterpret_cast<vf4*>(out + ((size_t)l * bt_total + bt) * DIM + c0) = w0;
    };

    // per-layer phase-1 body (prefetch + dots + state evolution)
    float fb[4][EPT], qb[2][EPT];
    auto p1_body = [&](int l) {
        const int m   = l / 3;
        const int i   = l - 3 * m;
        const int off = OFF_TAB[l];
        const int pf  = l & 3;
        const int pq  = l & 1;

        float qwv[EPT];
        #pragma unroll
        for (int j = 0; j < EPT; ++j) qwv[j] = qb[pq][j] * wv[j];
        float fC[EPT];
        if (l < LAYERS - 1) {
            #pragma unroll
            for (int j = 0; j < EPT; ++j) fC[j] = fb[pf][j];
        }

        if (l + 4 <= LAYERS - 2) {
            vf4 u0 = __builtin_nontemporal_load(
                reinterpret_cast<const vf4*>(lop + (size_t)(l + 4) * lstride));
            fb[pf][0]=u0.x; fb[pf][1]=u0.y; fb[pf][2]=u0.z; fb[pf][3]=u0.w;
        }
        if (l + 2 <= LAYERS - 1) {
            vf4 v0 = *reinterpret_cast<const vf4*>(qry + (size_t)(l + 2) * DIM + c0);
            qb[pq][0]=v0.x; qb[pq][1]=v0.y; qb[pq][2]=v0.z; qb[pq][3]=v0.w;
        }

        // dot(emb, qw)
        {
            float dv = e[0]*qwv[0] + e[1]*qwv[1] + e[2]*qwv[2] + e[3]*qwv[3];
            wred(dv, off);
        }
        // dot(S_s, qw); at i==0 the newest S (s=m-1) is still in f32 `part`
        #pragma unroll
        for (int s = 0; s < NBLK - 1; ++s) {
            if (s < m) {
                float dv;
                if (s == m - 1 && i == 0) {
                    dv = part[0]*qwv[0] + part[1]*qwv[1]
                       + part[2]*qwv[2] + part[3]*qwv[3];
                } else {
                    dv = upk(Spk[s][0],0)*qwv[0] + upk(Spk[s][0],1)*qwv[1]
                       + upk(Spk[s][1],0)*qwv[2] + upk(Spk[s][1],1)*qwv[3];
                }
                wred(dv, off + 1 + s);
            }
        }
        if (i > 0) {
            float dv = part[0]*qwv[0] + part[1]*qwv[1]
                     + part[2]*qwv[2] + part[3]*qwv[3];
            float sq = part[0]*part[0] + part[1]*part[1]
                     + part[2]*part[2] + part[3]*part[3];
            wred(dv, off + m + 1);
            wred(sq, off + m + 2);
            const int si = 2 * m + (i - 1);
            pp[si][0] = pk2(part[0], part[1]);
            pp[si][1] = pk2(part[2], part[3]);
        } else {
            float sq = part[0]*part[0] + part[1]*part[1]
                     + part[2]*part[2] + part[3]*part[3];
            wred(sq, off + m + 1);
        }

        if (l < LAYERS - 1) {
            if (i == 0) {
                #pragma unroll
                for (int j = 0; j < EPT; ++j) part[j] = fC[j];
            } else {
                #pragma unroll
                for (int j = 0; j < EPT; ++j) part[j] += fC[j];
            }
            if (i == 2 && m < NBLK - 1) {
                Spk[m][0] = pk2(part[0], part[1]);
                Spk[m][1] = pk2(part[2], part[3]);
            }
        }
    };

    // fused join+softmax: group grp handles layer l=grp (gl..gh). Lane s joins
    // its dot/ssq slots directly from red[][], then DPP softmax across group.
    auto grp_softmax = [&](int gl, int gh) {
        const int l = grp;
        if (l >= gl && l <= gh) {
            const int s = lane & 15;
            const int m = l / 3;
            const int i = l - 3 * m;
            const int nsrc = 1 + m + (i > 0 ? 1 : 0);
            // off(l) closed form (matches OFF_TAB)
            const int n = l - 1;
            const int t = n / 3;
            const int f = 3 * t * (t - 1) / 2 + (n % 3 + 1) * t;
            const int off = 1 + 2 * n + f + n - n / 3;
            const bool act = (s < nsrc);
            int dotslot = act ? off + s : 0;
            // ssqslot: emb->0; S_{s-1} -> 9s+3s(s-1)/2; partial -> off+s+1
            int ssqslot = 0;
            if (act && s > 0)
                ssqslot = (s <= m) ? (9 * s + 3 * s * (s - 1) / 2) : (off + s + 1);
            float dot = 0.f, sq = 0.f;
            #pragma unroll
            for (int g = 0; g < 32; ++g) {
                dot += red[g][dotslot];
                sq  += red[g][ssqslot];
            }
            float sc = act ? dot * rsqrtf(sq * invD + EPSV) : -3.0e38f;
            const float mx = grp16_max(sc);
            const float ee = act ? __expf(sc - mx) : 0.f;
            const float den = grp16_sum(ee);
            if (act) ab[l][s] = ee / den;
        }
    };

    // ========== BATCH A: layers 0..7 ==========
    {
        vf4 u0 = __builtin_nontemporal_load(reinterpret_cast<const vf4*>(lop));
        part[0]=u0.x; part[1]=u0.y; part[2]=u0.z; part[3]=u0.w;

        vf4 w0; w0.x=e[0]; w0.y=e[1]; w0.z=e[2]; w0.w=e[3];
        *reinterpret_cast<vf4*>(out + (size_t)bt * DIM + c0) = w0;

        float sq = e[0]*e[0] + e[1]*e[1] + e[2]*e[2] + e[3]*e[3];
        wred(sq, 0);
    }
    {   // prefetch init: f layers 1..4, q layers 1..2
        #pragma unroll
        for (int k = 1; k <= 4; ++k) {
            vf4 u = __builtin_nontemporal_load(
                reinterpret_cast<const vf4*>(lop + (size_t)k * lstride));
            fb[k & 3][0]=u.x; fb[k & 3][1]=u.y; fb[k & 3][2]=u.z; fb[k & 3][3]=u.w;
        }
        vf4 q;
        q = *reinterpret_cast<const vf4*>(qry + (size_t)1 * DIM + c0);
        qb[1][0]=q.x; qb[1][1]=q.y; qb[1][2]=q.z; qb[1][3]=q.w;
        q = *reinterpret_cast<const vf4*>(qry + (size_t)2 * DIM + c0);
        qb[0][0]=q.x; qb[0][1]=q.y; qb[0][2]=q.z; qb[0][3]=q.w;
    }
    #pragma unroll
    for (int l = 1; l <= 7; ++l) p1_body(l);

    __syncthreads();                       // A partials ready
    grp_softmax(1, 7);
    __syncthreads();                       // A alphas ready

    // ========== BATCH B (layers 8..15) + emit A outputs (1..7) ==========
    #pragma unroll
    for (int l = 8; l <= 15; ++l) {
        p1_body(l);
        if (l <= 14) emit(l - 7);          // A stores overlap B loads
    }

    __syncthreads();                       // B partials ready
    grp_softmax(8, 15);
    __syncthreads();                       // B alphas ready

    // ========== BATCH C (layers 16..23) + emit B outputs (8..15) ==========
    #pragma unroll
    for (int l = 16; l <= 23; ++l) {
        p1_body(l);
        emit(l - 8);                       // B stores overlap C loads
    }

    __syncthreads();                       // C partials ready
    grp_softmax(16, 23);
    __syncthreads();                       // C alphas ready

    // ========== emit C outputs (16..23) ==========
    #pragma unroll
    for (int l = 16; l <= 23; ++l) emit(l);
}

extern "C" void kernel_launch(void* const* d_in, const int* in_sizes, int n_in,
                              void* d_out, int out_size, void* d_ws, size_t ws_size,
                              hipStream_t stream) {
    const float* lo  = (const float*)d_in[0];  // layer_outputs (L,B,T,D)
    const float* emb = (const float*)d_in[1];  // embedding (B,T,D)
    const float* qry = (const float*)d_in[2];  // queries (L,D)
    const float* wgt = (const float*)d_in[3];  // key_norm_weight (D)
    float* outp = (float*)d_out;

    const int bt_total = in_sizes[1] / DIM;    // B*T

    block_attn_res_kernel<<<bt_total, TPB, 0, stream>>>(
        lo, emb, qry, wgt, outp, bt_total);
}

// Round 15
// 172.845 us; speedup vs baseline: 1.0380x; 1.0380x over previous
//
#include <hip/hip_runtime.h>
#include <hip/hip_bf16.h>

constexpr int LAYERS = 24;
constexpr int DIM    = 2048;
constexpr int NBLK   = 8;
constexpr float EPSV = 1e-6f;
constexpr int TPB    = 512;
constexpr int EPT    = 4;            // one float4 slice per thread
constexpr int NSLOT  = 147;          // total block-wide reduced scalars
constexpr int RSTR   = NSLOT + 2;    // odd stride

typedef float vf4 __attribute__((ext_vector_type(4)));

// Reduced-value layout (slot indices):
//   slot 0: ssq(emb)
//   layer l (1..23), m=l/3, i=l%3, off=OFF_TAB[l]:
//     off+0        : dot(emb, qw_l)
//     off+1+s      : dot(S_s, qw_l)          s = 0..m-1
//     i>0:  off+m+1: dot(part_l, qw_l),  off+m+2: ssq(part_l)
//     i==0: off+m+1: ssq(S_{m-1})
// Batches: A=layers 1..7 slots [0,27), B=8..15 [27,76), C=16..23 [76,147)
__device__ constexpr int OFF_TAB[24] =
    {0,1,4,7,10,14,18,22,27,32,37,43,49,55,62,69,76,84,92,100,109,118,127,137};

__device__ __forceinline__ unsigned pk2(float a, float b) {
    __hip_bfloat162 h2(__float2bfloat16(a), __float2bfloat16(b));
    union { __hip_bfloat162 h; unsigned u; } c; c.h = h2; return c.u;
}
__device__ __forceinline__ float upk(unsigned p, int hi) {
    union { unsigned u; float f; } c;
    c.u = hi ? (p & 0xffff0000u) : (p << 16);
    return c.f;
}

// DPP tree ops over each 16-lane group (pure VALU, no DS pipe).
template<int CTRL>
__device__ __forceinline__ float dpp_nbor(float x) {
    int y = __builtin_amdgcn_update_dpp(0, __float_as_int(x), CTRL, 0xF, 0xF, true);
    return __int_as_float(y);
}
__device__ __forceinline__ float grp16_sum(float x) {
    x += dpp_nbor<0xB1>(x);     // quad_perm[1,0,3,2]
    x += dpp_nbor<0x4E>(x);     // quad_perm[2,3,0,1]
    x += dpp_nbor<0x141>(x);    // row_half_mirror
    x += dpp_nbor<0x140>(x);    // row_mirror
    return x;
}
__device__ __forceinline__ float grp16_max(float x) {
    x = fmaxf(x, dpp_nbor<0xB1>(x));
    x = fmaxf(x, dpp_nbor<0x4E>(x));
    x = fmaxf(x, dpp_nbor<0x141>(x));
    x = fmaxf(x, dpp_nbor<0x140>(x));
    return x;
}

__global__ void __launch_bounds__(TPB, 4)   // cap 128 unified regs; demand ~108
block_attn_res_kernel(const float* __restrict__ lo,   // (L, B*T, D)
                      const float* __restrict__ emb,  // (B*T, D)
                      const float* __restrict__ qry,  // (L, D)
                      const float* __restrict__ wgt,  // (D)
                      float* __restrict__ out,        // (L, B*T, D)
                      int bt_total)
{
    const int bt   = blockIdx.x;
    const int tid  = threadIdx.x;
    const int lane = tid & 63;
    const int wid  = tid >> 6;
    const int grp  = (wid << 2) | (lane >> 4);   // 16-lane group id, 0..31
    const int c0   = tid * 4;                    // thread owns d-indices [4t,4t+4)

    __shared__ float red[32][RSTR];        // group partials (written once per slot)
    __shared__ float ab[LAYERS][12];       // normalized alphas per layer

    const float invD = 1.f / (float)DIM;
    const size_t lstride = (size_t)bt_total * DIM;
    const float* lop = lo + (size_t)bt * DIM + c0;

    // 16-lane DPP tree sum; group leader writes LDS
    auto wred = [&](float x, int slot) {
        x = grp16_sum(x);
        if ((lane & 15) == 0) red[grp][slot] = x;
    };

    // weight slice (folded into q row per layer)
    float wv[EPT];
    {
        vf4 w0 = *reinterpret_cast<const vf4*>(wgt + c0);
        wv[0]=w0.x; wv[1]=w0.y; wv[2]=w0.z; wv[3]=w0.w;
    }

    // ---- embedding slice
    float e[EPT];
    {
        vf4 v0 = __builtin_nontemporal_load(
            reinterpret_cast<const vf4*>(emb + (size_t)bt * DIM + c0));
        e[0]=v0.x; e[1]=v0.y; e[2]=v0.z; e[3]=v0.w;
    }

    unsigned pp[16][EPT/2];       // part snapshots at the 16 i>0 layers, bf16x2
    unsigned Spk[NBLK-1][EPT/2];  // finished block sums S_0..S_6, bf16x2
    float part[EPT];              // running within-block partial (f32)

    // output emission for one layer (l compile-time under unroll)
    auto emit = [&](int l) {
        const int m = l / 3;
        const int i = l - 3 * m;
        float h[EPT];
        {
            const float a0 = ab[l][0];
            #pragma unroll
            for (int j = 0; j < EPT; ++j) h[j] = a0 * e[j];
        }
        #pragma unroll
        for (int s = 0; s < NBLK - 1; ++s) {
            if (s < m) {
                const float a = ab[l][1 + s];
                h[0] += a * upk(Spk[s][0],0);
                h[1] += a * upk(Spk[s][0],1);
                h[2] += a * upk(Spk[s][1],0);
                h[3] += a * upk(Spk[s][1],1);
            }
        }
        if (i > 0) {
            const float a = ab[l][1 + m];
            const int si = 2 * m + (i - 1);
            h[0] += a * upk(pp[si][0],0);
            h[1] += a * upk(pp[si][0],1);
            h[2] += a * upk(pp[si][1],0);
            h[3] += a * upk(pp[si][1],1);
        }
        vf4 w0; w0.x=h[0]; w0.y=h[1]; w0.z=h[2]; w0.w=h[3];
        *reinterpret_cast<vf4*>(out + ((size_t)l * bt_total + bt) * DIM + c0) = w0;
    };

    // 4-deep double-buffers; q issued BEFORE f each body so the vmcnt wait on
    // q(l) never force-drains younger f loads (vmcnt is issue-ordered).
    float fb[4][EPT], qb[4][EPT];
    auto p1_body = [&](int l) {
        const int m   = l / 3;
        const int i   = l - 3 * m;
        const int off = OFF_TAB[l];
        const int pf  = l & 3;

        float qwv[EPT];
        #pragma unroll
        for (int j = 0; j < EPT; ++j) qwv[j] = qb[pf][j] * wv[j];
        float fC[EPT];
        if (l < LAYERS - 1) {
            #pragma unroll
            for (int j = 0; j < EPT; ++j) fC[j] = fb[pf][j];
        }

        // issue next prefetches: q first, then f (both 4-deep)
        if (l + 4 <= LAYERS - 1) {
            vf4 v0 = *reinterpret_cast<const vf4*>(qry + (size_t)(l + 4) * DIM + c0);
            qb[pf][0]=v0.x; qb[pf][1]=v0.y; qb[pf][2]=v0.z; qb[pf][3]=v0.w;
        }
        if (l + 4 <= LAYERS - 2) {
            vf4 u0 = __builtin_nontemporal_load(
                reinterpret_cast<const vf4*>(lop + (size_t)(l + 4) * lstride));
            fb[pf][0]=u0.x; fb[pf][1]=u0.y; fb[pf][2]=u0.z; fb[pf][3]=u0.w;
        }

        // dot(emb, qw)
        {
            float dv = e[0]*qwv[0] + e[1]*qwv[1] + e[2]*qwv[2] + e[3]*qwv[3];
            wred(dv, off);
        }
        // dot(S_s, qw); at i==0 the newest S (s=m-1) is still in f32 `part`
        #pragma unroll
        for (int s = 0; s < NBLK - 1; ++s) {
            if (s < m) {
                float dv;
                if (s == m - 1 && i == 0) {
                    dv = part[0]*qwv[0] + part[1]*qwv[1]
                       + part[2]*qwv[2] + part[3]*qwv[3];
                } else {
                    dv = upk(Spk[s][0],0)*qwv[0] + upk(Spk[s][0],1)*qwv[1]
                       + upk(Spk[s][1],0)*qwv[2] + upk(Spk[s][1],1)*qwv[3];
                }
                wred(dv, off + 1 + s);
            }
        }
        if (i > 0) {
            float dv = part[0]*qwv[0] + part[1]*qwv[1]
                     + part[2]*qwv[2] + part[3]*qwv[3];
            float sq = part[0]*part[0] + part[1]*part[1]
                     + part[2]*part[2] + part[3]*part[3];
            wred(dv, off + m + 1);
            wred(sq, off + m + 2);
            const int si = 2 * m + (i - 1);
            pp[si][0] = pk2(part[0], part[1]);
            pp[si][1] = pk2(part[2], part[3]);
        } else {
            float sq = part[0]*part[0] + part[1]*part[1]
                     + part[2]*part[2] + part[3]*part[3];
            wred(sq, off + m + 1);
        }

        if (l < LAYERS - 1) {
            if (i == 0) {
                #pragma unroll
                for (int j = 0; j < EPT; ++j) part[j] = fC[j];
            } else {
                #pragma unroll
                for (int j = 0; j < EPT; ++j) part[j] += fC[j];
            }
            if (i == 2 && m < NBLK - 1) {
                Spk[m][0] = pk2(part[0], part[1]);
                Spk[m][1] = pk2(part[2], part[3]);
            }
        }
    };

    // fused join+softmax: group grp handles layer l=grp. Lane s joins its
    // dot/ssq slots directly from red[][], then DPP softmax across the group.
    auto grp_softmax = [&](int gl, int gh) {
        const int l = grp;
        if (l >= gl && l <= gh) {
            const int s = lane & 15;
            const int m = l / 3;
            const int i = l - 3 * m;
            const int nsrc = 1 + m + (i > 0 ? 1 : 0);
            // off(l) closed form (matches OFF_TAB)
            const int n = l - 1;
            const int t = n / 3;
            const int f = 3 * t * (t - 1) / 2 + (n % 3 + 1) * t;
            const int off = 1 + 2 * n + f + n - n / 3;
            const bool act = (s < nsrc);
            int dotslot = act ? off + s : 0;
            // ssqslot: emb->0; S_{s-1} -> 9s+3s(s-1)/2; partial -> off+s+1
            int ssqslot = 0;
            if (act && s > 0)
                ssqslot = (s <= m) ? (9 * s + 3 * s * (s - 1) / 2) : (off + s + 1);
            float dot = 0.f, sq = 0.f;
            #pragma unroll
            for (int g = 0; g < 32; ++g) {
                dot += red[g][dotslot];
                sq  += red[g][ssqslot];
            }
            float sc = act ? dot * rsqrtf(sq * invD + EPSV) : -3.0e38f;
            const float mx = grp16_max(sc);
            const float ee = act ? __expf(sc - mx) : 0.f;
            const float den = grp16_sum(ee);
            if (act) ab[l][s] = ee / den;
        }
    };

    // ========== BATCH A: layers 0..7 ==========
    {
        vf4 u0 = __builtin_nontemporal_load(reinterpret_cast<const vf4*>(lop));
        part[0]=u0.x; part[1]=u0.y; part[2]=u0.z; part[3]=u0.w;

        vf4 w0; w0.x=e[0]; w0.y=e[1]; w0.z=e[2]; w0.w=e[3];
        *reinterpret_cast<vf4*>(out + (size_t)bt * DIM + c0) = w0;

        float sq = e[0]*e[0] + e[1]*e[1] + e[2]*e[2] + e[3]*e[3];
        wred(sq, 0);
    }
    {   // prologue prefetch, interleaved q,f per layer 1..4
        #pragma unroll
        for (int k = 1; k <= 4; ++k) {
            vf4 q = *reinterpret_cast<const vf4*>(qry + (size_t)k * DIM + c0);
            qb[k & 3][0]=q.x; qb[k & 3][1]=q.y; qb[k & 3][2]=q.z; qb[k & 3][3]=q.w;
            vf4 u = __builtin_nontemporal_load(
                reinterpret_cast<const vf4*>(lop + (size_t)k * lstride));
            fb[k & 3][0]=u.x; fb[k & 3][1]=u.y; fb[k & 3][2]=u.z; fb[k & 3][3]=u.w;
        }
    }
    #pragma unroll
    for (int l = 1; l <= 7; ++l) p1_body(l);

    __syncthreads();                       // A partials ready
    grp_softmax(1, 7);
    __syncthreads();                       // A alphas ready

    // ========== BATCH B (layers 8..15) + emit A outputs (1..7) ==========
    #pragma unroll
    for (int l = 8; l <= 15; ++l) {
        p1_body(l);
        if (l <= 14) emit(l - 7);          // A stores overlap B loads
    }

    __syncthreads();                       // B partials ready
    grp_softmax(8, 15);
    __syncthreads();                       // B alphas ready

    // ========== BATCH C (layers 16..23) + emit B outputs (8..15) ==========
    #pragma unroll
    for (int l = 16; l <= 23; ++l) {
        p1_body(l);
        emit(l - 8);                       // B stores overlap C loads
    }

    __syncthreads();                       // C partials ready
    grp_softmax(16, 23);
    __syncthreads();                       // C alphas ready

    // ========== emit C outputs (16..23) ==========
    #pragma unroll
    for (int l = 16; l <= 23; ++l) emit(l);
}

extern "C" void kernel_launch(void* const* d_in, const int* in_sizes, int n_in,
                              void* d_out, int out_size, void* d_ws, size_t ws_size,
                              hipStream_t stream) {
    const float* lo  = (const float*)d_in[0];  // layer_outputs (L,B,T,D)
    const float* emb = (const float*)d_in[1];  // embedding (B,T,D)
    const float* qry = (const float*)d_in[2];  // queries (L,D)
    const float* wgt = (const float*)d_in[3];  // key_norm_weight (D)
    float* outp = (float*)d_out;

    const int bt_total = in_sizes[1] / DIM;    // B*T

    block_attn_res_kernel<<<bt_total, TPB, 0, stream>>>(
        lo, emb, qry, wgt, outp, bt_total);
}